// Round 10
// baseline (254.231 us; speedup 1.0000x reference)
//
#include <hip/hip_runtime.h>

#define DIM 128
#define HEADS 8
#define PHC 16

// bucket sort: 64 nodes per bucket, padded per-bucket regions
#define BSHIFT 6
#define BNODES 64
#define CAP 1408     // mean fill = E*64/n ~ 1024, sigma ~ 32; +12 sigma
#define NBMAX 1600   // >= ceil(n/64)

typedef __bf16 bf16x4 __attribute__((ext_vector_type(4)));
typedef __bf16 bf16x8 __attribute__((ext_vector_type(8)));
typedef float  f32x4  __attribute__((ext_vector_type(4)));

__device__ inline unsigned short f2bf(float x) {
  unsigned int u = __float_as_uint(x);
  unsigned int r = (u + 0x7FFF + ((u >> 16) & 1)) >> 16;  // round-to-nearest-even
  return (unsigned short)r;
}

// ---------------------------------------------------------------------------
// Kernel 0: pre-pack W into bf16 hi/lo B-fragments in MFMA fragment order,
// and zero the bucket cursors (must precede the fused gemm+scatter kernel).
// ---------------------------------------------------------------------------
__global__ __launch_bounds__(256) void k_prepw(
    const float* __restrict__ W, __bf16* __restrict__ Wh,
    __bf16* __restrict__ Wl, int* __restrict__ gCursor, int NB) {
  const int tuple = blockIdx.x * 256 + threadIdx.x;   // 0..2047
  if (tuple < NB) gCursor[tuple] = 0;
  const int ln = tuple & 15;
  const int lg = (tuple >> 4) & 3;
  const int cg = (tuple >> 6) & 7;
  const int kt = tuple >> 9;
  const int col = (cg << 4) + ln;
  bf16x8 h, l;
#pragma unroll
  for (int e = 0; e < 8; ++e) {
    int k = (kt << 5) + ((e >> 2) << 4) + (lg << 2) + (e & 3);
    float wv = W[k * DIM + col];
    __bf16 hh = (__bf16)wv;
    h[e] = hh;
    l[e] = (__bf16)(wv - (float)hh);
  }
  *(bf16x8*)(Wh + tuple * 8) = h;
  *(bf16x8*)(Wl + tuple * 8) = l;
}

// ---------------------------------------------------------------------------
// Kernel 1 (FUSED): role-split grid. Blocks [0, nScat) bucket the edge list;
// blocks [nScat, ...) run the MFMA GEMM. nt is written into 4 HEAD-PAIR
// planes nt_hp[hp][node][32ch bf16 = 64B record] plus paired exp weights
// s_exp_hp[hp][node][2 floats]. (R7/R9-proven: absmax 0.015625.)
// ---------------------------------------------------------------------------
#define GROWS 64

__global__ __launch_bounds__(256, 3) void k_gemm_scatter(
    const float* __restrict__ A, const __bf16* __restrict__ Wh,
    const __bf16* __restrict__ Wl, const float* __restrict__ bias,
    const float* __restrict__ attn_w, unsigned int* __restrict__ nt_hp,
    float* __restrict__ s_exp_hp, const int* __restrict__ send,
    const int* __restrict__ recv, int* __restrict__ gCursor,
    unsigned int* __restrict__ pairs, int E, int NB, int nScat, int n) {
  __shared__ __align__(16) float smemF[GROWS * DIM];   // 32 KB, aliased

  if (blockIdx.x < nScat) {
    // ---------------- scatter role: bucket edges by recv>>6 ----------------
    int* cnt = (int*)smemF;
    int* cur = cnt + NBMAX;           // 12.8 KB of the 32 KB
    const int t = threadIdx.x;
    for (int i = t; i < NB; i += 256) cnt[i] = 0;
    __syncthreads();
    const int e0 = blockIdx.x * 8192;
    const int e1 = min(e0 + 8192, E);
    for (int i = e0 + t; i < e1; i += 256)
      atomicAdd(&cnt[recv[i] >> BSHIFT], 1);
    __syncthreads();
    for (int i = t; i < NB; i += 256) {
      int c = cnt[i];
      cur[i] = i * CAP + (c ? atomicAdd(&gCursor[i], c) : 0);
    }
    __syncthreads();
    for (int i = e0 + t; i < e1; i += 256) {
      int r = recv[i];
      int b = r >> BSHIFT;
      int p = atomicAdd(&cur[b], 1);
      if (p - b * CAP < CAP)   // overflow guard (P ~ 0 at +12 sigma)
        pairs[p] = (unsigned int)send[i] | ((unsigned int)(r & (BNODES - 1)) << 17);
    }
    return;
  }

  // ------------------------------ gemm role -------------------------------
  __bf16* Ah = (__bf16*)smemF;          // [64 rows][16 units][8] bf16 hi
  __bf16* Al = Ah + GROWS * DIM;        // same, lo
  const int t    = threadIdx.x;
  const int row0 = (blockIdx.x - nScat) * GROWS;
  const int lane = t & 63;
  const int w    = t >> 6;       // wave id: cols [32w, 32w+32)
  const int lg   = lane >> 4;    // k-group
  const int ln   = lane & 15;    // fragment row (A) / col (B,D)

  // ---- A-tile global loads
  float4 av[8];
  {
    const float4* A4 = (const float4*)(A + (size_t)row0 * DIM);
    const int lim = min(GROWS, n - row0) * (DIM / 4);
#pragma unroll
    for (int j = 0; j < 8; ++j) {
      int i = t + j * 256;
      av[j] = (i < lim) ? A4[i] : make_float4(0.f, 0.f, 0.f, 0.f);
    }
  }

  // ---- convert to bf16 hi/lo, store fragment-ordered + swizzled.
#pragma unroll
  for (int j = 0; j < 8; ++j) {
    int i = t + j * 256;
    int r = i >> 5, c4 = i & 31;
    int ktc = c4 >> 3, lgc = c4 & 3, ehi = (c4 >> 2) & 1;
    int unit = (r << 4) + (((ktc << 2) + lgc) ^ (r & 15));
    int ei = (unit << 3) + (ehi << 2);
    float x0 = av[j].x, x1 = av[j].y, x2 = av[j].z, x3 = av[j].w;
    __bf16 h0 = (__bf16)x0, h1 = (__bf16)x1, h2 = (__bf16)x2, h3 = (__bf16)x3;
    bf16x4 hv = {h0, h1, h2, h3};
    bf16x4 lv = {(__bf16)(x0 - (float)h0), (__bf16)(x1 - (float)h1),
                 (__bf16)(x2 - (float)h2), (__bf16)(x3 - (float)h3)};
    *(bf16x4*)(Ah + ei) = hv;
    *(bf16x4*)(Al + ei) = lv;
  }

  f32x4 acc[4][2];
  {
    const float b0 = bias[(w << 5) + ln];
    const float b1 = bias[(w << 5) + 16 + ln];
#pragma unroll
    for (int rt = 0; rt < 4; ++rt) {
      acc[rt][0] = (f32x4){b0, b0, b0, b0};
      acc[rt][1] = (f32x4){b1, b1, b1, b1};
    }
  }
  __syncthreads();

  // ---- main loop: 4 k-steps x {4 W vec-loads, 8 ds_read_b128, 24 MFMA}
  const int cg0 = w << 1;
#pragma unroll
  for (int kt = 0; kt < 4; ++kt) {
    bf16x8 Bh0, Bl0, Bh1, Bl1;
    {
      int i0 = ((((kt << 3) + cg0) << 2) + lg) * 16 + ln;      // ct = 0
      int i1 = ((((kt << 3) + cg0 + 1) << 2) + lg) * 16 + ln;  // ct = 1
      Bh0 = *(const bf16x8*)(Wh + (i0 << 3));
      Bl0 = *(const bf16x8*)(Wl + (i0 << 3));
      Bh1 = *(const bf16x8*)(Wh + (i1 << 3));
      Bl1 = *(const bf16x8*)(Wl + (i1 << 3));
    }
    bf16x8 ah[4], al[4];
#pragma unroll
    for (int rt = 0; rt < 4; ++rt) {
      int m = (rt << 4) + ln;
      int u = (m << 4) + (((kt << 2) + lg) ^ (m & 15));
      ah[rt] = *(const bf16x8*)(Ah + (u << 3));
      al[rt] = *(const bf16x8*)(Al + (u << 3));
    }
#pragma unroll
    for (int rt = 0; rt < 4; ++rt) {
      acc[rt][0] = __builtin_amdgcn_mfma_f32_16x16x32_bf16(ah[rt], Bh0, acc[rt][0], 0, 0, 0);
      acc[rt][0] = __builtin_amdgcn_mfma_f32_16x16x32_bf16(ah[rt], Bl0, acc[rt][0], 0, 0, 0);
      acc[rt][0] = __builtin_amdgcn_mfma_f32_16x16x32_bf16(al[rt], Bh0, acc[rt][0], 0, 0, 0);
      acc[rt][1] = __builtin_amdgcn_mfma_f32_16x16x32_bf16(ah[rt], Bh1, acc[rt][1], 0, 0, 0);
      acc[rt][1] = __builtin_amdgcn_mfma_f32_16x16x32_bf16(ah[rt], Bl1, acc[rt][1], 0, 0, 0);
      acc[rt][1] = __builtin_amdgcn_mfma_f32_16x16x32_bf16(al[rt], Bh1, acc[rt][1], 0, 0, 0);
    }
  }

  __syncthreads();   // all waves done with Ah/Al -> reuse LDS as f32 scratch

  // ---- scatter D-fragments to LDS f32 [64][128] (col bit4 ^= row bit2)
#pragma unroll
  for (int rt = 0; rt < 4; ++rt)
#pragma unroll
    for (int ct = 0; ct < 2; ++ct) {
      int colx = ((w << 5) + (ct << 4) + ln) ^ ((lg & 1) << 4);
#pragma unroll
      for (int r = 0; r < 4; ++r) {
        int rowl = (rt << 4) + (lg << 2) + r;
        smemF[(rowl << 7) + colx] = acc[rt][ct][r];
      }
    }

  // ---- sender scores from register fragments -> paired exp planes.
  //      receiver part + attn_b cancel in the segment softmax; |score|<=~6.
  {
    const float aw = attn_w[ln];
#pragma unroll
    for (int rt = 0; rt < 4; ++rt)
#pragma unroll
      for (int ct = 0; ct < 2; ++ct) {
        // head = 2w + ct -> head-pair hp = w, parity = ct
#pragma unroll
        for (int r = 0; r < 4; ++r) {
          float v = acc[rt][ct][r];
          float p = (v > 0.f ? v : 0.2f * v) * aw;
          p += __shfl_xor(p, 1);
          p += __shfl_xor(p, 2);
          p += __shfl_xor(p, 4);
          p += __shfl_xor(p, 8);
          if (ln == 0) {
            int row = row0 + (rt << 4) + (lg << 2) + r;
            if (row < n) s_exp_hp[((size_t)w * n + row) * 2 + ct] = __expf(p);
          }
        }
      }
  }
  __syncthreads();

  // ---- pack to bf16 from LDS into head-pair planes:
  //      nt_hp[hp][node][32ch] (64B record). Same f2bf rounding -> absmax
  //      unchanged. Each j writes one head's 16ch slice of its pair plane.
  {
    const int nrow = min(GROWS, n - row0);
    const int r = t >> 2;           // 0..63 row in tile
    const int q = t & 3;            // 4-ch group within the head slice
    if (r < nrow) {
#pragma unroll
      for (int j = 0; j < 8; ++j) { // j = head
        int c4 = (j << 2) + q;
        int c4s = c4 ^ (((r >> 2) & 1) << 2);   // undo col-bit4 swizzle
        f32x4 v = *(const f32x4*)(smemF + (r << 7) + (c4s << 2));
        unsigned int lo = (unsigned int)f2bf(v[0]) | ((unsigned int)f2bf(v[1]) << 16);
        unsigned int hi = (unsigned int)f2bf(v[2]) | ((unsigned int)f2bf(v[3]) << 16);
        ((uint2*)nt_hp)[((size_t)(j >> 1) * n + row0 + r) * 8 + (j & 1) * 4 + q] =
            make_uint2(lo, hi);
      }
    }
  }
}

// ---------------------------------------------------------------------------
// Kernel 2: FUSED build + aggregate. Grid NB*4, block = (bucket, head-pair).
// NEW: the in-LDS CSR scatter uses per-(node, sender>>14) cursors so each
// node's edge list is stored COARSE-SORTED BY SENDER RANGE. All teams at
// loop progress f then access senders near quantile f (degree-sorted slots
// give similar loop lengths) -> the chip-wide hot window of the 6.4 MB plane
// is ~1-2 MB and L2-fits, converting the R9-measured 220 MB of fabric misses
// into ~compulsory traffic. Aggregate loop itself is byte-identical to R9
// (no padding waste, unlike hard per-node quarter loops).
// ---------------------------------------------------------------------------
__global__ __launch_bounds__(256) void k_aggbuild(
    const unsigned int* __restrict__ pairs, const int* __restrict__ gCursor,
    const unsigned int* __restrict__ nt_hp, const float* __restrict__ s_exp_hp,
    float* __restrict__ out, int n) {
  __shared__ unsigned int buf[CAP];
  __shared__ int csr_l[CAP];
  __shared__ int hist8[BNODES * 8];   // per (node, sender>>14) counts
  __shared__ int cur8[BNODES * 8];    // scatter cursors
  __shared__ unsigned int slotmeta[BNODES];
  const int b  = blockIdx.x >> 2;
  const int hp = blockIdx.x & 3;    // head pair; blockIdx%8 ~ XCD round-robin
  const int t = threadIdx.x;
  const int base = b * CAP;
  const int bsize = min(gCursor[b], CAP);

  // ---- build phase (hides under the gather's memory time, per R6/R9)
  for (int i = t; i < bsize; i += 256)
    buf[i] = __builtin_nontemporal_load(&pairs[base + i]);
  hist8[t] = 0;
  hist8[t + 256] = 0;
  __syncthreads();
  for (int i = t; i < bsize; i += 256) {
    unsigned int v = buf[i];
    atomicAdd(&hist8[(((v >> 17) & 63) << 3) + ((v & 0x1FFFF) >> 14)], 1);
  }
  __syncthreads();
  if (t < 64) {   // wave 0: node totals, scan, counting-rank, range offsets
    int h[8];
    int v = 0;
#pragma unroll
    for (int r = 0; r < 8; ++r) {
      h[r] = hist8[(t << 3) + r];
      v += h[r];
    }
    int x = v;
#pragma unroll
    for (int off = 1; off < 64; off <<= 1) {
      int y = __shfl_up(x, off);
      if (t >= off) x += y;
    }
    int e = x - v;          // exclusive offset of this node's segment
    int run = e;
#pragma unroll
    for (int r = 0; r < 8; ++r) {   // per-sender-range cursors within segment
      cur8[(t << 3) + r] = run;
      run += h[r];
    }
    int rank = 0;
    for (int j = 0; j < 64; ++j) {
      int dj = __shfl(v, j);
      rank += (dj > v) || (dj == v && j < t);
    }
    slotmeta[rank] = ((unsigned int)e << 17) | ((unsigned int)v << 6) |
                     (unsigned int)t;
  }
  __syncthreads();
  for (int i = t; i < bsize; i += 256) {
    unsigned int v = buf[i];
    int p = atomicAdd(&cur8[(((v >> 17) & 63) << 3) + ((v & 0x1FFFF) >> 14)], 1);
    csr_l[p] = (int)(v & 0x1FFFF);
  }
  __syncthreads();

  // ---- aggregate phase: 8-lane team per degree-sorted slot (as R9)
  const int lane8 = t & 7;        // owns channels 4*lane8 .. +3 of the 32
  const int par   = lane8 >> 2;   // head parity within the pair
  const uint2* nt2 = (const uint2*)nt_hp;
  const size_t pb8 = (size_t)hp * n * 8;        // plane base, uint2 units
  const float* spp = s_exp_hp + (size_t)hp * n * 2;

#pragma unroll 1
  for (int pi = 0; pi < 2; ++pi) {
    const int nl = (t >> 3) + (pi << 5);        // degree-sorted slot
    const unsigned int m = slotmeta[nl];
    const int node = (b << BSHIFT) + (int)(m & 63);
    const int deg  = (int)((m >> 6) & 0x7FF);
    const int eoff = (int)(m >> 17);
    f32x4 a = {0.f, 0.f, 0.f, 0.f};
    float den = 0.f;
    for (int j = 0; j < deg; j += 8) {
      int   ss[8];
      float ww[8];
      uint2 qq[8];
#pragma unroll
      for (int u = 0; u < 8; ++u) {
        bool ok = (j + u) < deg;
        ss[u] = csr_l[ok ? (eoff + j + u) : eoff];
        ww[u] = ok ? spp[ss[u] * 2 + par] : 0.f;  // 8B line / team
        qq[u] = nt2[pb8 + ss[u] * 8 + lane8];     // 64B line / team
      }
#pragma unroll
      for (int u = 0; u < 8; ++u) {
        den += ww[u];
        a.x = fmaf(ww[u], __uint_as_float(qq[u].x << 16), a.x);
        a.y = fmaf(ww[u], __uint_as_float(qq[u].x & 0xFFFF0000u), a.y);
        a.z = fmaf(ww[u], __uint_as_float(qq[u].y << 16), a.z);
        a.w = fmaf(ww[u], __uint_as_float(qq[u].y & 0xFFFF0000u), a.w);
      }
    }
    if (node < n) {
      const float inv = (deg > 0) ? 1.0f / den : 0.f;  // deg==0 -> zeros
      f32x4 o = {a.x * inv, a.y * inv, a.z * inv, a.w * inv};
      // out[node][32*hp + 4*lane8 .. +3]: 128B contiguous per team
      __builtin_nontemporal_store(
          o, (f32x4*)out + (size_t)node * 32 + (hp << 3) + lane8);
    }
  }
}

// ---------------------------------------------------------------------------
extern "C" void kernel_launch(void* const* d_in, const int* in_sizes, int n_in,
                              void* d_out, int out_size, void* d_ws, size_t ws_size,
                              hipStream_t stream) {
  const float* nodes   = (const float*)d_in[0];
  const int*   senders = (const int*)d_in[1];
  const int*   recvs   = (const int*)d_in[2];
  const float* W       = (const float*)d_in[3];
  const float* bias    = (const float*)d_in[4];
  const float* attn_w  = (const float*)d_in[5];
  // d_in[6] = attn_b: cancels in segment softmax, unused.

  const int n = in_sizes[0] / DIM;   // 100000
  const int E = in_sizes[1];         // 1600000
  const int NB = (n + BNODES - 1) >> BSHIFT;   // 1563 buckets

  char* w = (char*)d_ws;
  auto align256 = [](size_t x) { return (x + 255) & ~(size_t)255; };
  size_t off = 0;
  unsigned int* nt_hp = (unsigned int*)(w + off); off += align256((size_t)n * DIM * 2);
  float* s_exp_hp = (float*)(w + off); off += align256((size_t)n * HEADS * 4);
  unsigned int* pairs = (unsigned int*)(w + off); off += align256((size_t)NB * CAP * 4);
  int* gCursor   = (int*)(w + off);   off += align256((size_t)NB * 4);
  __bf16* Wh     = (__bf16*)(w + off); off += align256((size_t)2048 * 8 * 2);
  __bf16* Wl     = (__bf16*)(w + off); off += align256((size_t)2048 * 8 * 2);
  (void)ws_size;

  k_prepw<<<8, 256, 0, stream>>>(W, Wh, Wl, gCursor, NB);
  const int nScat = (E + 8191) / 8192;                 // 196 scatter blocks
  const int ngemm = (n + GROWS - 1) / GROWS;           // 1563 gemm blocks
  k_gemm_scatter<<<nScat + ngemm, 256, 0, stream>>>(
      nodes, Wh, Wl, bias, attn_w, nt_hp, s_exp_hp,
      senders, recvs, gCursor, pairs, E, NB, nScat, n);
  k_aggbuild<<<NB * 4, 256, 0, stream>>>(pairs, gCursor, nt_hp, s_exp_hp,
                                         (float*)d_out, n);
}

// Round 11
// 244.962 us; speedup vs baseline: 1.0378x; 1.0378x over previous
//
#include <hip/hip_runtime.h>

#define DIM 128
#define HEADS 8
#define PHC 16

// bucket sort: 64 nodes per bucket, padded per-bucket regions
#define BSHIFT 6
#define BNODES 64
#define CAP 1408     // mean fill = E*64/n ~ 1024, sigma ~ 32; +12 sigma
#define NBMAX 1600   // >= ceil(n/64)

typedef __bf16 bf16x4 __attribute__((ext_vector_type(4)));
typedef __bf16 bf16x8 __attribute__((ext_vector_type(8)));
typedef float  f32x4  __attribute__((ext_vector_type(4)));

__device__ inline unsigned short f2bf(float x) {
  unsigned int u = __float_as_uint(x);
  unsigned int r = (u + 0x7FFF + ((u >> 16) & 1)) >> 16;  // round-to-nearest-even
  return (unsigned short)r;
}

// ---------------------------------------------------------------------------
// Kernel 0: pre-pack W into bf16 hi/lo B-fragments in MFMA fragment order,
// and zero the bucket cursors (must precede the fused gemm+scatter kernel).
// ---------------------------------------------------------------------------
__global__ __launch_bounds__(256) void k_prepw(
    const float* __restrict__ W, __bf16* __restrict__ Wh,
    __bf16* __restrict__ Wl, int* __restrict__ gCursor, int NB) {
  const int tuple = blockIdx.x * 256 + threadIdx.x;   // 0..2047
  if (tuple < NB) gCursor[tuple] = 0;
  const int ln = tuple & 15;
  const int lg = (tuple >> 4) & 3;
  const int cg = (tuple >> 6) & 7;
  const int kt = tuple >> 9;
  const int col = (cg << 4) + ln;
  bf16x8 h, l;
#pragma unroll
  for (int e = 0; e < 8; ++e) {
    int k = (kt << 5) + ((e >> 2) << 4) + (lg << 2) + (e & 3);
    float wv = W[k * DIM + col];
    __bf16 hh = (__bf16)wv;
    h[e] = hh;
    l[e] = (__bf16)(wv - (float)hh);
  }
  *(bf16x8*)(Wh + tuple * 8) = h;
  *(bf16x8*)(Wl + tuple * 8) = l;
}

// ---------------------------------------------------------------------------
// Kernel 1 (FUSED): role-split grid. Blocks [0, nScat) bucket the edge list
// (independent of the GEMM); blocks [nScat, ...) run the MFMA GEMM with
// row-major bf16 nt + s_exp[node][8] epilogue (R2/R4-proven layout: the
// full-256B-row gather achieved the best fabric rate, 3.59 TB/s).
// ---------------------------------------------------------------------------
#define GROWS 64

__global__ __launch_bounds__(256, 3) void k_gemm_scatter(
    const float* __restrict__ A, const __bf16* __restrict__ Wh,
    const __bf16* __restrict__ Wl, const float* __restrict__ bias,
    const float* __restrict__ attn_w, unsigned int* __restrict__ nt_bf,
    float* __restrict__ s_exp, const int* __restrict__ send,
    const int* __restrict__ recv, int* __restrict__ gCursor,
    unsigned int* __restrict__ pairs, int E, int NB, int nScat, int n) {
  __shared__ __align__(16) float smemF[GROWS * DIM];   // 32 KB, aliased

  if (blockIdx.x < nScat) {
    // ---------------- scatter role: bucket edges by recv>>6 ----------------
    int* cnt = (int*)smemF;
    int* cur = cnt + NBMAX;           // 12.8 KB of the 32 KB
    const int t = threadIdx.x;
    for (int i = t; i < NB; i += 256) cnt[i] = 0;
    __syncthreads();
    const int e0 = blockIdx.x * 8192;
    const int e1 = min(e0 + 8192, E);
    for (int i = e0 + t; i < e1; i += 256)
      atomicAdd(&cnt[recv[i] >> BSHIFT], 1);
    __syncthreads();
    for (int i = t; i < NB; i += 256) {
      int c = cnt[i];
      cur[i] = i * CAP + (c ? atomicAdd(&gCursor[i], c) : 0);
    }
    __syncthreads();
    for (int i = e0 + t; i < e1; i += 256) {
      int r = recv[i];
      int b = r >> BSHIFT;
      int p = atomicAdd(&cur[b], 1);
      if (p - b * CAP < CAP)   // overflow guard (P ~ 0 at +12 sigma)
        pairs[p] = (unsigned int)send[i] | ((unsigned int)(r & (BNODES - 1)) << 17);
    }
    return;
  }

  // ------------------------------ gemm role -------------------------------
  __bf16* Ah = (__bf16*)smemF;          // [64 rows][16 units][8] bf16 hi
  __bf16* Al = Ah + GROWS * DIM;        // same, lo
  const int t    = threadIdx.x;
  const int row0 = (blockIdx.x - nScat) * GROWS;
  const int lane = t & 63;
  const int w    = t >> 6;       // wave id: cols [32w, 32w+32)
  const int lg   = lane >> 4;    // k-group
  const int ln   = lane & 15;    // fragment row (A) / col (B,D)

  // ---- A-tile global loads
  float4 av[8];
  {
    const float4* A4 = (const float4*)(A + (size_t)row0 * DIM);
    const int lim = min(GROWS, n - row0) * (DIM / 4);
#pragma unroll
    for (int j = 0; j < 8; ++j) {
      int i = t + j * 256;
      av[j] = (i < lim) ? A4[i] : make_float4(0.f, 0.f, 0.f, 0.f);
    }
  }

  // ---- convert to bf16 hi/lo, store fragment-ordered + swizzled.
#pragma unroll
  for (int j = 0; j < 8; ++j) {
    int i = t + j * 256;
    int r = i >> 5, c4 = i & 31;
    int ktc = c4 >> 3, lgc = c4 & 3, ehi = (c4 >> 2) & 1;
    int unit = (r << 4) + (((ktc << 2) + lgc) ^ (r & 15));
    int ei = (unit << 3) + (ehi << 2);
    float x0 = av[j].x, x1 = av[j].y, x2 = av[j].z, x3 = av[j].w;
    __bf16 h0 = (__bf16)x0, h1 = (__bf16)x1, h2 = (__bf16)x2, h3 = (__bf16)x3;
    bf16x4 hv = {h0, h1, h2, h3};
    bf16x4 lv = {(__bf16)(x0 - (float)h0), (__bf16)(x1 - (float)h1),
                 (__bf16)(x2 - (float)h2), (__bf16)(x3 - (float)h3)};
    *(bf16x4*)(Ah + ei) = hv;
    *(bf16x4*)(Al + ei) = lv;
  }

  f32x4 acc[4][2];
  {
    const float b0 = bias[(w << 5) + ln];
    const float b1 = bias[(w << 5) + 16 + ln];
#pragma unroll
    for (int rt = 0; rt < 4; ++rt) {
      acc[rt][0] = (f32x4){b0, b0, b0, b0};
      acc[rt][1] = (f32x4){b1, b1, b1, b1};
    }
  }
  __syncthreads();

  // ---- main loop: 4 k-steps x {4 W vec-loads, 8 ds_read_b128, 24 MFMA}
  const int cg0 = w << 1;
#pragma unroll
  for (int kt = 0; kt < 4; ++kt) {
    bf16x8 Bh0, Bl0, Bh1, Bl1;
    {
      int i0 = ((((kt << 3) + cg0) << 2) + lg) * 16 + ln;      // ct = 0
      int i1 = ((((kt << 3) + cg0 + 1) << 2) + lg) * 16 + ln;  // ct = 1
      Bh0 = *(const bf16x8*)(Wh + (i0 << 3));
      Bl0 = *(const bf16x8*)(Wl + (i0 << 3));
      Bh1 = *(const bf16x8*)(Wh + (i1 << 3));
      Bl1 = *(const bf16x8*)(Wl + (i1 << 3));
    }
    bf16x8 ah[4], al[4];
#pragma unroll
    for (int rt = 0; rt < 4; ++rt) {
      int m = (rt << 4) + ln;
      int u = (m << 4) + (((kt << 2) + lg) ^ (m & 15));
      ah[rt] = *(const bf16x8*)(Ah + (u << 3));
      al[rt] = *(const bf16x8*)(Al + (u << 3));
    }
#pragma unroll
    for (int rt = 0; rt < 4; ++rt) {
      acc[rt][0] = __builtin_amdgcn_mfma_f32_16x16x32_bf16(ah[rt], Bh0, acc[rt][0], 0, 0, 0);
      acc[rt][0] = __builtin_amdgcn_mfma_f32_16x16x32_bf16(ah[rt], Bl0, acc[rt][0], 0, 0, 0);
      acc[rt][0] = __builtin_amdgcn_mfma_f32_16x16x32_bf16(al[rt], Bh0, acc[rt][0], 0, 0, 0);
      acc[rt][1] = __builtin_amdgcn_mfma_f32_16x16x32_bf16(ah[rt], Bh1, acc[rt][1], 0, 0, 0);
      acc[rt][1] = __builtin_amdgcn_mfma_f32_16x16x32_bf16(ah[rt], Bl1, acc[rt][1], 0, 0, 0);
      acc[rt][1] = __builtin_amdgcn_mfma_f32_16x16x32_bf16(al[rt], Bh1, acc[rt][1], 0, 0, 0);
    }
  }

  __syncthreads();   // all waves done with Ah/Al -> reuse LDS as f32 scratch

  // ---- scatter D-fragments to LDS f32 [64][128] (col bit4 ^= row bit2)
#pragma unroll
  for (int rt = 0; rt < 4; ++rt)
#pragma unroll
    for (int ct = 0; ct < 2; ++ct) {
      int colx = ((w << 5) + (ct << 4) + ln) ^ ((lg & 1) << 4);
#pragma unroll
      for (int r = 0; r < 4; ++r) {
        int rowl = (rt << 4) + (lg << 2) + r;
        smemF[(rowl << 7) + colx] = acc[rt][ct][r];
      }
    }

  // ---- sender scores from register fragments.
  //      receiver part + attn_b cancel in the segment softmax; |score|<=~6.
  {
    const float aw = attn_w[ln];
#pragma unroll
    for (int rt = 0; rt < 4; ++rt)
#pragma unroll
      for (int ct = 0; ct < 2; ++ct) {
        const int head = (w << 1) + ct;
#pragma unroll
        for (int r = 0; r < 4; ++r) {
          float v = acc[rt][ct][r];
          float p = (v > 0.f ? v : 0.2f * v) * aw;
          p += __shfl_xor(p, 1);
          p += __shfl_xor(p, 2);
          p += __shfl_xor(p, 4);
          p += __shfl_xor(p, 8);
          if (ln == 0) {
            int row = row0 + (rt << 4) + (lg << 2) + r;
            if (row < n) s_exp[row * HEADS + head] = __expf(p);
          }
        }
      }
  }
  __syncthreads();

  // ---- pack to bf16 from LDS, coalesced uint2 stores, row-major nt
  //      (same rounding as the fp32 kernel -> absmax unchanged)
  {
    const int nrow = min(GROWS, n - row0);
#pragma unroll
    for (int j = 0; j < 8; ++j) {
      int i = t + j * 256;
      int r = i >> 5, c4 = i & 31;
      if (r < nrow) {
        int c4s = c4 ^ (((r >> 2) & 1) << 2);   // undo col-bit4 swizzle
        f32x4 v = *(const f32x4*)(smemF + (r << 7) + (c4s << 2));
        unsigned int lo = (unsigned int)f2bf(v[0]) | ((unsigned int)f2bf(v[1]) << 16);
        unsigned int hi = (unsigned int)f2bf(v[2]) | ((unsigned int)f2bf(v[3]) << 16);
        ((uint2*)nt_bf)[(size_t)(row0 + r) * 32 + c4] = make_uint2(lo, hi);
      }
    }
  }
}

// ---------------------------------------------------------------------------
// Kernel 2: FUSED build + aggregate, R2 STRUCTURE (measured optimum of the
// 10-round design space: 8M line-reqs, 3.59 TB/s fabric rate, 87.4 us):
// one block per bucket, quarter-wave (16 lanes x uint4) per node = full
// 256B sequential row per edge, x4 edge unroll. Plus the later wins:
// shfl-based degree rank-sort (slots stratified pi*16+wv*4+q so each wave
// samples all degree quartiles -> no max-of-4-Poisson tail).
// hp/head splits are strictly dominated (R5: 2x reqs; R7-R10: +60% reqs,
// same fabric bytes, worse streaming) — do not revisit.
// ---------------------------------------------------------------------------
__device__ inline void acc8(float wgt, uint4 qv, float4& a0, float4& a1) {
  a0.x = fmaf(wgt, __uint_as_float(qv.x << 16), a0.x);
  a0.y = fmaf(wgt, __uint_as_float(qv.x & 0xFFFF0000u), a0.y);
  a0.z = fmaf(wgt, __uint_as_float(qv.y << 16), a0.z);
  a0.w = fmaf(wgt, __uint_as_float(qv.y & 0xFFFF0000u), a0.w);
  a1.x = fmaf(wgt, __uint_as_float(qv.z << 16), a1.x);
  a1.y = fmaf(wgt, __uint_as_float(qv.z & 0xFFFF0000u), a1.y);
  a1.z = fmaf(wgt, __uint_as_float(qv.w << 16), a1.z);
  a1.w = fmaf(wgt, __uint_as_float(qv.w & 0xFFFF0000u), a1.w);
}

__global__ __launch_bounds__(256) void k_aggbuild(
    const unsigned int* __restrict__ pairs, const int* __restrict__ gCursor,
    const unsigned int* __restrict__ nt_bf, const float* __restrict__ s_exp,
    float* __restrict__ out, int n) {
  __shared__ unsigned int buf[CAP];
  __shared__ int csr_l[CAP];
  __shared__ int hist[BNODES], curl[BNODES];
  __shared__ unsigned int slotmeta[BNODES];
  const int b = blockIdx.x;
  const int t = threadIdx.x;
  const int base = b * CAP;
  const int bsize = min(gCursor[b], CAP);

  // ---- build phase (hides under the gather's memory time, per R6/R9)
  for (int i = t; i < bsize; i += 256)
    buf[i] = __builtin_nontemporal_load(&pairs[base + i]);
  if (t < BNODES) hist[t] = 0;
  __syncthreads();
  for (int i = t; i < bsize; i += 256)
    atomicAdd(&hist[(buf[i] >> 17) & (BNODES - 1)], 1);
  __syncthreads();
  if (t < 64) {   // wave 0: scan for offsets + shfl counting-rank by degree
    int v = hist[t];
    int x = v;
#pragma unroll
    for (int off = 1; off < 64; off <<= 1) {
      int y = __shfl_up(x, off);
      if (t >= off) x += y;
    }
    int e = x - v;          // exclusive offset
    curl[t] = e;
    int rank = 0;
    for (int j = 0; j < 64; ++j) {
      int dj = __shfl(v, j);
      rank += (dj > v) || (dj == v && j < t);
    }
    slotmeta[rank] = ((unsigned int)e << 17) | ((unsigned int)v << 6) |
                     (unsigned int)t;
  }
  __syncthreads();
  for (int i = t; i < bsize; i += 256) {
    unsigned int v = buf[i];
    int p = atomicAdd(&curl[(v >> 17) & (BNODES - 1)], 1);
    csr_l[p] = (int)(v & 0x1FFFF);
  }
  __syncthreads();

  // ---- aggregate: quarter-wave per degree-sorted slot, 16 nodes/pass
  const int wv   = t >> 6;
  const int lane = t & 63;
  const int q    = lane >> 4;     // quarter id
  const int l16  = lane & 15;     // owns channels 8*l16 .. 8*l16+7
  const int head = l16 >> 1;
  const uint4* nt4 = (const uint4*)nt_bf;

#pragma unroll 1
  for (int pi = 0; pi < 4; ++pi) {
    const int slot = (pi << 4) + (wv << 2) + q;   // stratified over quartiles
    const unsigned int m = slotmeta[slot];
    const int node = (b << BSHIFT) + (int)(m & 63);
    const int deg  = (int)((m >> 6) & 0x7FF);
    const int eoff = (int)(m >> 17);
    float4 a0 = make_float4(0.f, 0.f, 0.f, 0.f);
    float4 a1 = make_float4(0.f, 0.f, 0.f, 0.f);
    float den = 0.f;
    for (int j = 0; j < deg; j += 4) {
      bool ok1 = (j + 1) < deg, ok2 = (j + 2) < deg, ok3 = (j + 3) < deg;
      int s0 = csr_l[eoff + j];                   // LDS broadcast (16 lanes)
      int s1 = csr_l[ok1 ? (eoff + j + 1) : eoff];
      int s2 = csr_l[ok2 ? (eoff + j + 2) : eoff];
      int s3 = csr_l[ok3 ? (eoff + j + 3) : eoff];
      float w0 = s_exp[s0 * HEADS + head];        // 32B line / team
      float w1 = ok1 ? s_exp[s1 * HEADS + head] : 0.f;
      float w2 = ok2 ? s_exp[s2 * HEADS + head] : 0.f;
      float w3 = ok3 ? s_exp[s3 * HEADS + head] : 0.f;
      uint4 q0 = nt4[(size_t)s0 * 16 + l16];      // 256 B/row sequential
      uint4 q1 = nt4[(size_t)s1 * 16 + l16];
      uint4 q2 = nt4[(size_t)s2 * 16 + l16];
      uint4 q3 = nt4[(size_t)s3 * 16 + l16];
      den += (w0 + w1) + (w2 + w3);
      acc8(w0, q0, a0, a1);
      acc8(w1, q1, a0, a1);
      acc8(w2, q2, a0, a1);
      acc8(w3, q3, a0, a1);
    }
    if (node < n) {
      const float inv = (deg > 0) ? 1.0f / den : 0.f;  // deg==0 -> zeros
      float4* op = (float4*)out + (size_t)node * 32 + l16 * 2;
      op[0] = make_float4(a0.x * inv, a0.y * inv, a0.z * inv, a0.w * inv);
      op[1] = make_float4(a1.x * inv, a1.y * inv, a1.z * inv, a1.w * inv);
    }
  }
}

// ---------------------------------------------------------------------------
extern "C" void kernel_launch(void* const* d_in, const int* in_sizes, int n_in,
                              void* d_out, int out_size, void* d_ws, size_t ws_size,
                              hipStream_t stream) {
  const float* nodes   = (const float*)d_in[0];
  const int*   senders = (const int*)d_in[1];
  const int*   recvs   = (const int*)d_in[2];
  const float* W       = (const float*)d_in[3];
  const float* bias    = (const float*)d_in[4];
  const float* attn_w  = (const float*)d_in[5];
  // d_in[6] = attn_b: cancels in segment softmax, unused.

  const int n = in_sizes[0] / DIM;   // 100000
  const int E = in_sizes[1];         // 1600000
  const int NB = (n + BNODES - 1) >> BSHIFT;   // 1563 buckets

  char* w = (char*)d_ws;
  auto align256 = [](size_t x) { return (x + 255) & ~(size_t)255; };
  size_t off = 0;
  unsigned int* nt_bf = (unsigned int*)(w + off); off += align256((size_t)n * DIM * 2);
  float* s_exp   = (float*)(w + off); off += align256((size_t)n * HEADS * 4);
  unsigned int* pairs = (unsigned int*)(w + off); off += align256((size_t)NB * CAP * 4);
  int* gCursor   = (int*)(w + off);   off += align256((size_t)NB * 4);
  __bf16* Wh     = (__bf16*)(w + off); off += align256((size_t)2048 * 8 * 2);
  __bf16* Wl     = (__bf16*)(w + off); off += align256((size_t)2048 * 8 * 2);
  (void)ws_size;

  k_prepw<<<8, 256, 0, stream>>>(W, Wh, Wl, gCursor, NB);
  const int nScat = (E + 8191) / 8192;                 // 196 scatter blocks
  const int ngemm = (n + GROWS - 1) / GROWS;           // 1563 gemm blocks
  k_gemm_scatter<<<nScat + ngemm, 256, 0, stream>>>(
      nodes, Wh, Wl, bias, attn_w, nt_bf, s_exp,
      senders, recvs, gCursor, pairs, E, NB, nScat, n);
  k_aggbuild<<<NB, 256, 0, stream>>>(pairs, gCursor, nt_bf, s_exp,
                                     (float*)d_out, n);
}